// Round 13
// baseline (146.108 us; speedup 1.0000x reference)
//
#include <hip/hip_runtime.h>
#include <math.h>

#define DET 512
#define NB  16
#define NT  180
#define PI_D 3.14159265358979323846
#define NPAIR 89
#define PADQ 108
#define NGP  45                  // pair-rows gp=0..44 (col gp | col 88-gp)
#define NENT 768                 // 16B entries per pair-row
#define ROWB 12288               // bytes per pair-row (768 x 16)
#define NOFF 101                 // off-diagonal transpose-pair units (a < bt)
#define NMRG 6                   // merged-diagonal blocks (2 diagonals each)
#define NBX  108                 // 101 off-diag + 6 merged-diag + 1 zeroer

// ws layout (bytes):
//   [XF0,+32K)     xf0[b][512]  f32   filtered row t=0
//   [XF90,+32K)    xf90[b][512] f32   filtered row t=90
//   [PK,+8.9M)     pkq[b][gp][768] uint4 entries:
//                  {Tft2[i],Tfu2[i],Uft2[i],Ufu2[i]}, each dword = f16 pair
//                  {v[i], v[i+1]} — pre-paired for v_dot2_f32_f16.
#define TT_OFF   8192
#define XF0_OFF  (TT_OFF + 512*512*2)
#define XF90_OFF (XF0_OFF + 32768)
#define PK_OFF   (XF90_OFF + 32768)

typedef _Float16 half8  __attribute__((ext_vector_type(8)));
typedef _Float16 half4v __attribute__((ext_vector_type(4)));
typedef _Float16 half2v __attribute__((ext_vector_type(2)));
typedef float    float4v __attribute__((ext_vector_type(4)));

__device__ inline half2v H2(unsigned u) { half2v h; __builtin_memcpy(&h, &u, 4); return h; }
__device__ inline half2v pkrtz(float a, float b) {
  auto r = __builtin_amdgcn_cvt_pkrtz(a, b);     // __fp16 vec2 -> bit-cast
  half2v h; __builtin_memcpy(&h, &r, 4); return h;
}
__device__ inline float fdot2f(half2v a, half2v b, float c) {
  return __builtin_amdgcn_fdot2(a, b, c, false);   // 2 f16 FMAs / slot, f32 acc
}

// ---------------- Filter (MFMA GEMM) + pre-paired f16 packing ----------------
// R13 (= R12 + type fix): pack layout pre-pairs consecutive detector taps per
// dword so backproj's lerp is ONE v_dot2_f32_f16. Each value lands in two
// entries (lo of en, hi of en-1) via 2B stores — block-boundary pairs compose
// race-free (disjoint bytes).
__global__ __launch_bounds__(256) void filter_kernel(const float* __restrict__ x,
                                                     char* __restrict__ wsb) {
  __shared__ _Float16 xs_h[16][512];
  __shared__ _Float16 xs_l[16][512];
  __shared__ float xfs[16][65];
  __shared__ _Float16 wls[8][1032];      // Toeplitz shift-copies (R8)
  char* pkb = wsb + PK_OFF;

  int tid = threadIdx.x;
  int p = blockIdx.x, b = blockIdx.y;
  int dt0 = blockIdx.z * 2;

  // ---- Toeplitz shift-copies ----
  {
    int k0 = tid * 4;
    const float CSC = (float)(-2048.0 / (PI_D * PI_D));
#pragma unroll
    for (int r = 0; r < 8; r++) {
      half4v v;
#pragma unroll
      for (int j = 0; j < 4; j++) {
        int delta = 511 - (k0 + j) - r;
        float wv;
        if (delta == 0) wv = 512.0f;
        else if (delta & 1) wv = CSC / (float)(delta * delta);
        else wv = 0.0f;
        v[j] = (_Float16)wv;
      }
      *(half4v*)&wls[r][k0] = v;
    }
  }

  int m = tid & 15, kp = tid >> 4;
  int tS;
  if (p < 11) tS = (m < 8) ? (8 * p + 1 + m) : (164 - 8 * p + m);
  else        tS = (m == 0) ? 89 : ((m == 1) ? 91 : ((m == 3) ? 90 : 0));
  const float* xb = x + (size_t)b * DET * NT + tS;
#pragma unroll 8
  for (int pass = 0; pass < 16; pass++) {
    int k = pass * 32 + kp * 2;
    int c = k >> 3, h = k & 7;
    int phys = (((c ^ (m & 7)) << 3) | h);
    float v0 = xb[(size_t)k * NT];
    float v1 = xb[(size_t)(k + 1) * NT];
    _Float16 h0 = (_Float16)v0, h1 = (_Float16)v1;
    half2v hh = {h0, h1};
    half2v ll = {(_Float16)(v0 - (float)h0), (_Float16)(v1 - (float)h1)};
    *(half2v*)&xs_h[m][phys] = hh;
    *(half2v*)&xs_l[m][phys] = ll;
  }
  __syncthreads();   // covers xs staging AND wls fill

  int nprb = (p < 11) ? 8 : 1;
  int tpb0 = (p < 11) ? 8 * p : 88;
  if (blockIdx.z == 0) {
    // zero pads. Full 16B: entries [0,107) and [620,768). Partial (2B stores,
    // disjoint from pack's byte positions): entry 107 lo-halves, 619 hi-halves.
    for (int pr = 0; pr < nprb; pr++) {
      int tq = (p < 11) ? (tpb0 + pr) : 88;
      int gp = (tq <= 44) ? tq : 88 - tq;
      char* base = pkb + ((size_t)b * NGP + gp) * ROWB;
      if (tid < 107) {
        uint4 z4 = {0u, 0u, 0u, 0u};
        *(uint4*)(base + (size_t)tid * 16) = z4;
      } else if (tid < 255) {
        uint4 z4 = {0u, 0u, 0u, 0u};
        *(uint4*)(base + (size_t)(620 + tid - 107) * 16) = z4;
      } else {
        unsigned short z = 0;
        *(unsigned short*)(base + 107*16 + 0)  = z; *(unsigned short*)(base + 107*16 + 4)  = z;
        *(unsigned short*)(base + 107*16 + 8)  = z; *(unsigned short*)(base + 107*16 + 12) = z;
        *(unsigned short*)(base + 619*16 + 2)  = z; *(unsigned short*)(base + 619*16 + 6)  = z;
        *(unsigned short*)(base + 619*16 + 10) = z; *(unsigned short*)(base + 619*16 + 14) = z;
      }
    }
  }

  int lane = tid & 63, wv = tid >> 6;
  int mm = lane & 15, q = lane >> 4;
  const _Float16* arh = &xs_h[mm][0];
  const _Float16* arl = &xs_l[mm][0];
  int e = mm & 7;
  int mp = tid >> 5, cc = (tid & 31) * 2;
  int rT = (p < 11) ? mp : 0;
  int rU = (p < 11) ? (15 - mp) : 1;
  int tpp = (p < 11) ? (8 * p + mp) : 88;
  bool dopack = (p < 11) || (mp == 0);
  int gp_  = (tpp <= 44) ? tpp : 88 - tpp;
  int so   = (tpp <= 44) ? 0 : 8;        // T dwords at +0/+4, U at +8/+12

  for (int dti = 0; dti < 2; dti++) {
    int dt = dt0 + dti;
    int dw = dt * 64 + wv * 16 + mm;
    int sdw = 511 - dw;
    const _Float16* thl = &wls[sdw & 7][sdw & ~7];
    float4v acc0 = {0.f, 0.f, 0.f, 0.f};
    float4v acc1 = {0.f, 0.f, 0.f, 0.f};
#pragma unroll 4
    for (int kc = 0; kc < 512; kc += 32) {
      int ph = ((((kc >> 3) + q) ^ e) << 3);
      half8 Ah = *(const half8*)&arh[ph];
      half8 Al = *(const half8*)&arl[ph];
      half8 Bh = *(const half8*)&thl[kc + q * 8];
      acc0 = __builtin_amdgcn_mfma_f32_16x16x32_f16(Ah, Bh, acc0, 0, 0, 0);
      acc1 = __builtin_amdgcn_mfma_f32_16x16x32_f16(Al, Bh, acc1, 0, 0, 0);
    }
    if (dti > 0) __syncthreads();
#pragma unroll
    for (int i = 0; i < 4; i++)
      xfs[q * 4 + i][wv * 16 + mm] = (acc0[i] + acc1[i]) * 0.0009765625f;
    __syncthreads();
    if (dopack) {
      char* base = pkb + ((size_t)b * NGP + gp_) * ROWB;
#pragma unroll
      for (int ci = 0; ci < 2; ci++) {
        int c = cc + ci;
        _Float16 ftc = (_Float16)xfs[rT][c];
        _Float16 fuc = (_Float16)xfs[rU][c];
        int en = PADQ + dt * 64 + c;
        *(_Float16*)(base + (size_t)en * 16 + 0 + so)       = ftc;  // lo ft2[en]
        *(_Float16*)(base + (size_t)(en - 1) * 16 + 2 + so) = ftc;  // hi ft2[en-1]
        *(_Float16*)(base + (size_t)en * 16 + 4 + so)       = fuc;
        *(_Float16*)(base + (size_t)(en - 1) * 16 + 6 + so) = fuc;
        if (tpp == 44) {               // self-paired row: duplicate into U
          *(_Float16*)(base + (size_t)en * 16 + 8)        = ftc;
          *(_Float16*)(base + (size_t)(en - 1) * 16 + 10) = ftc;
          *(_Float16*)(base + (size_t)en * 16 + 12)       = fuc;
          *(_Float16*)(base + (size_t)(en - 1) * 16 + 14) = fuc;
        }
      }
    }
    if (p == 11 && tid < 64) {         // singles: row2=t0, row3=t90
      float* f0  = (float*)(wsb + XF0_OFF)  + (size_t)b * DET;
      float* f90 = (float*)(wsb + XF90_OFF) + (size_t)b * DET;
      f0[dt * 64 + tid]  = xfs[2][tid];
      f90[dt * 64 + tid] = xfs[3][tid];
    }
  }
}

// ---------------- Backprojection v17: fdot2 + pre-paired entries ----------------
// Per PROCESS: 4 aligned ds_read_b128 + 16 v_dot2_f32_f16 + 4 cvt_pkrtz (~33
// VALU slots, was ~45 with 32 v_fma_mix). LDS 24.6KB (2x12KB dbuf).
// Batch-pair XCD swizzle: b from f&15 so XCD k serves batches {2k,2k+1} —
// pkq working set 1.1MB/XCD stays L2-resident despite the doubled layout.
#define XTRACT(nm, qq, SW)                                                     \
  half2v Tft##nm = H2(SW ? qq.z : qq.x), Tfu##nm = H2(SW ? qq.w : qq.y);       \
  half2v Uft##nm = H2(SW ? qq.x : qq.z), Ufu##nm = H2(SW ? qq.y : qq.w);

#define PROCESS(c_, s_, SW)                                                    \
  {                                                                            \
    float inner = fmaf(-(s_), q_, 363.5f);                                     \
    float iyA = fmaf( (c_), p_, inner);                                        \
    float iyB = fmaf(-(c_), p_, inner);                                        \
    int   iA = (int)iyA;  float wA = __builtin_amdgcn_fractf(iyA);             \
    int   iB = (int)iyB;  float wB = __builtin_amdgcn_fractf(iyB);             \
    half2v wpA = pkrtz(1.f - wA, wA);                                          \
    half2v wpAr = pkrtz(wA, 1.f - wA);                                         \
    half2v wpB = pkrtz(1.f - wB, wB);                                          \
    half2v wpBr = pkrtz(wB, 1.f - wB);                                         \
    uint4 qA = colI[iA], qB = colI[iB];                                        \
    uint4 qMA = colI[726 - iA], qMB = colI[726 - iB];                          \
    XTRACT(A, qA, SW)  XTRACT(B, qB, SW)                                       \
    XTRACT(MA, qMA, SW) XTRACT(MB, qMB, SW)                                    \
    A1 = fdot2f(wpA, TftA, A1);   A1 = fdot2f(wpB, TfuB, A1);                  \
    A2 = fdot2f(wpB, TftB, A2);   A2 = fdot2f(wpA, TfuA, A2);                  \
    A3 = fdot2f(wpAr, TftMA, A3); A3 = fdot2f(wpBr, TfuMB, A3);                \
    A4 = fdot2f(wpBr, TftMB, A4); A4 = fdot2f(wpAr, TfuMA, A4);                \
    B1 = fdot2f(wpAr, UftMA, B1); B1 = fdot2f(wpB, UfuB, B1);                  \
    B2 = fdot2f(wpBr, UftMB, B2); B2 = fdot2f(wpA, UfuA, B2);                  \
    B3 = fdot2f(wpA, UftA, B3);   B3 = fdot2f(wpBr, UfuMB, B3);                \
    B4 = fdot2f(wpB, UftB, B4);   B4 = fdot2f(wpAr, UfuMA, B4);                \
  }

#define PROCESSP(c_, s_, SW, pp, qq_, AA1, AA2, AA3, AA4)                      \
  {                                                                            \
    float inner = fmaf(-(s_), (qq_), 363.5f);                                  \
    float iyA = fmaf( (c_), (pp), inner);                                      \
    float iyB = fmaf(-(c_), (pp), inner);                                      \
    int   iA = (int)iyA;  float wA = __builtin_amdgcn_fractf(iyA);             \
    int   iB = (int)iyB;  float wB = __builtin_amdgcn_fractf(iyB);             \
    half2v wpA = pkrtz(1.f - wA, wA);                                          \
    half2v wpAr = pkrtz(wA, 1.f - wA);                                         \
    half2v wpB = pkrtz(1.f - wB, wB);                                          \
    half2v wpBr = pkrtz(wB, 1.f - wB);                                         \
    uint4 qA = colI[iA], qB = colI[iB];                                        \
    uint4 qMA = colI[726 - iA], qMB = colI[726 - iB];                          \
    half2v TftA = H2(SW ? qA.z : qA.x),  TfuA = H2(SW ? qA.w : qA.y);          \
    half2v TftB = H2(SW ? qB.z : qB.x),  TfuB = H2(SW ? qB.w : qB.y);          \
    half2v TftMA = H2(SW ? qMA.z : qMA.x), TfuMA = H2(SW ? qMA.w : qMA.y);     \
    half2v TftMB = H2(SW ? qMB.z : qMB.x), TfuMB = H2(SW ? qMB.w : qMB.y);     \
    AA1 = fdot2f(wpA, TftA, AA1);   AA1 = fdot2f(wpB, TfuB, AA1);              \
    AA2 = fdot2f(wpB, TftB, AA2);   AA2 = fdot2f(wpA, TfuA, AA2);              \
    AA3 = fdot2f(wpAr, TftMA, AA3); AA3 = fdot2f(wpBr, TfuMB, AA3);            \
    AA4 = fdot2f(wpBr, TftMB, AA4); AA4 = fdot2f(wpAr, TfuMA, AA4);            \
  }

__global__ __launch_bounds__(256, 6) void backproj_kernel(
    const char* __restrict__ wsb, float* __restrict__ out) {
  __shared__ uint4 pk[2][NENT];     // 24576 B double-buffer
  __shared__ float2 trigs[48];
  int tid = threadIdx.x;
  // batch-pair XCD swizzle: XCD = f%8 serves b in {2k,2k+1}
  int f = blockIdx.x;
  int sub = f & 15;
  int b = 2 * (sub & 7) + (sub >> 3);
  int bx = f >> 4;                  // unit 0..107
  int lx = tid & 15, ly = tid >> 4;
  float* ob = out + (size_t)b * DET * DET;
  int w = tid >> 6, l = tid & 63;

  if (bx == NBX - 1) {
    // zero dead 16x16 tiles (a, bt<L[a]) and their 3 mirrors
    const int LDEAD[10] = {10,8,6,5,4,3,2,2,1,1};
    for (int a = 0; a < 10; a++)
      for (int bt = 0; bt < LDEAD[a]; bt++) {
        int X1 = 16*a + lx, X2 = 511 - X1;
        int Y1 = 16*bt + ly, Y2 = 511 - Y1;
        ob[(size_t)Y1*DET + X1] = 0.f;
        ob[(size_t)Y1*DET + X2] = 0.f;
        ob[(size_t)Y2*DET + X1] = 0.f;
        ob[(size_t)Y2*DET + X2] = 0.f;
      }
    return;
  }

  // pair trig: (cos t, sin t), t = tid+1 degrees
  if (tid < NGP) {
    float th = (float)(tid + 1) * (float)(PI_D / 180.0);
    float2 cs; cs.x = cosf(th); cs.y = sinf(th);
    trigs[tid] = cs;
  }

  const char* pkgb = wsb + PK_OFF + (size_t)b * NGP * ROWB;

  // stage pair-row g (12288 B): 12 chunks of 1024B, 3 per wave (16B/lane DMA)
  auto stage_group = [&](int g, int par) {
#pragma unroll
    for (int i = 0; i < 3; i++) {
      int c = w + 4 * i;
      const char* src = pkgb + (size_t)g * ROWB + c * 1024 + l * 16;
      char* dst = (char*)&pk[par][0] + c * 1024;
      __builtin_amdgcn_global_load_lds(
          (const __attribute__((address_space(1))) unsigned int*)src,
          (__attribute__((address_space(3))) unsigned int*)dst, 16, 0, 0);
    }
  };

  const float* f0  = (const float*)(wsb + XF0_OFF)  + (size_t)b * DET;
  const float* f90 = (const float*)(wsb + XF90_OFF) + (size_t)b * DET;
  const float SC = (float)(PI_D / 360.0);

  if (bx >= NOFF) {
    // ---- merged-diagonal block: two diagonal tiles, P-only ----
    int d = bx - NOFF;
    int a1 = 4 + 2 * d, a2 = 5 + 2 * d;
    float p1_ = (float)(16 * a1 + lx) - 255.5f, q1_ = (float)(16 * a1 + ly) - 255.5f;
    float p2_ = (float)(16 * a2 + lx) - 255.5f, q2_ = (float)(16 * a2 + ly) - 255.5f;
    int mk1 = 481 - 32 * a1, mn1 = 505 - 32 * a1 - 8 * w;
    int mk2 = 481 - 32 * a2, mn2 = 505 - 32 * a2 - 8 * w;
    bool wl1 = (mk1 * mk1 + mn1 * mn1 <= 261632);
    bool wl2 = (mk2 * mk2 + mn2 * mn2 <= 261632);

    float A1=0.f, A2=0.f, A3=0.f, A4=0.f;
    float C1=0.f, C2=0.f, C3=0.f, C4=0.f;

    stage_group(0, 0);
    __syncthreads();
    for (int g = 0; g < NGP; g++) {
      if (g + 1 < NGP) stage_group(g + 1, (g + 1) & 1);
      float2 cs = trigs[g];
      const uint4* colI = &pk[g & 1][0];
      if (wl1) {
        PROCESSP(cs.x, cs.y, 0, p1_, q1_, A1, A2, A3, A4);
        if (g != 44) PROCESSP(cs.y, cs.x, 1, p1_, q1_, A1, A2, A3, A4);
      }
      if (wl2) {
        PROCESSP(cs.x, cs.y, 0, p2_, q2_, C1, C2, C3, C4);
        if (g != 44) PROCESSP(cs.y, cs.x, 1, p2_, q2_, C1, C2, C3, C4);
      }
      __syncthreads();
    }
#pragma unroll
    for (int t = 0; t < 2; t++) {
      int a = t ? a2 : a1;
      int X1 = 16 * a + lx, X2 = 511 - X1;
      int Y1 = 16 * a + ly, Y2 = 511 - Y1;
      int kx = 2 * X1 - 511, ky = 2 * Y1 - 511;
      bool in = (kx * kx + ky * ky) <= 261632;
      float g0x1 = f0[X1], g0x2 = f0[X2];
      float g90y1 = f90[Y1], g90y2 = f90[Y2];
      float P1 = (t ? C1 : A1) + g0x1 + g90y2;
      float P2 = (t ? C2 : A2) + g0x2 + g90y2;
      float P3 = (t ? C3 : A3) + g0x2 + g90y1;
      float P4 = (t ? C4 : A4) + g0x1 + g90y1;
      ob[(size_t)Y1 * DET + X1] = in ? P1 * SC : 0.f;
      ob[(size_t)Y1 * DET + X2] = in ? P2 * SC : 0.f;
      ob[(size_t)Y2 * DET + X2] = in ? P3 * SC : 0.f;
      ob[(size_t)Y2 * DET + X1] = in ? P4 * SC : 0.f;
    }
    return;
  }

  // ---- off-diagonal unit (a < bt): P-quad + transposed Q-quad ----
  int a = (bx>=6)+(bx>=14)+(bx>=24)+(bx>=35)+(bx>=46)+(bx>=56)+(bx>=65)
        + (bx>=73)+(bx>=80)+(bx>=86)+(bx>=91)+(bx>=95)+(bx>=98)+(bx>=100);
  int Sa, bs;
  if (a < 8) { Sa = (int)((0x41382E23180E0600ULL >> (8*a)) & 0xFF);
               bs = (int)((0x080706050506080AULL >> (8*a)) & 0xFF); }
  else       { Sa = (int)((0x0064625F5B565049ULL >> (8*(a-8))) & 0xFF);
               bs = (int)((0x000F0E0D0C0B0A09ULL >> (8*(a-8))) & 0xFF); }
  int bt = bx - Sa + bs;
  int tx = 16*a, ty = 16*bt;

  int X1 = tx + lx, X2 = 511 - X1;
  int Y1 = ty + ly, Y2 = 511 - Y1;
  float p_ = (float)X1 - 255.5f;
  float q_ = (float)Y1 - 255.5f;

  int mkx = 481 - 32*a;
  int mky = 505 - 32*bt - 8*w;
  bool wlive = (mkx*mkx + mky*mky <= 261632);

  float A1=0.f, A2=0.f, A3=0.f, A4=0.f;   // P-tile mirrors
  float B1=0.f, B2=0.f, B3=0.f, B4=0.f;   // Q (transposed) tile mirrors

  stage_group(0, 0);
  __syncthreads();   // covers stage(0) AND trigs fill

  for (int g = 0; g < NGP; g++) {
    if (g + 1 < NGP) stage_group(g + 1, (g + 1) & 1);
    float2 cs = trigs[g];
    const uint4* colI = &pk[g & 1][0];
    if (wlive) {
      PROCESS(cs.x, cs.y, 0);                    // tp = g
      if (g != 44) PROCESS(cs.y, cs.x, 1);       // tp = 88-g
    }
    __syncthreads();
  }

  // epilogue: singles t=0 / t=90, mask, scale
  int kx = 2*X1 - 511, ky = 2*Y1 - 511;
  bool in = (kx*kx + ky*ky) <= 261632;

  float g0x1 = f0[X1], g0x2 = f0[X2];
  float g90y1 = f90[Y1], g90y2 = f90[Y2];
  float P1 = A1 + g0x1 + g90y2;
  float P2 = A2 + g0x2 + g90y2;
  float P3 = A3 + g0x2 + g90y1;
  float P4 = A4 + g0x1 + g90y1;
  ob[(size_t)Y1*DET + X1] = in ? P1*SC : 0.f;
  ob[(size_t)Y1*DET + X2] = in ? P2*SC : 0.f;
  ob[(size_t)Y2*DET + X2] = in ? P3*SC : 0.f;
  ob[(size_t)Y2*DET + X1] = in ? P4*SC : 0.f;

  {
    float g0y1 = f0[Y1], g0y2 = f0[Y2];
    float g90x1 = f90[X1], g90x2 = f90[X2];
    float Q1 = B1 + g0y1 + g90x2;
    float Q2 = B2 + g0y1 + g90x1;
    float Q3 = B3 + g0y2 + g90x1;
    float Q4 = B4 + g0y2 + g90x2;
    Q1 = in ? Q1*SC : 0.f;
    Q2 = in ? Q2*SC : 0.f;
    Q3 = in ? Q3*SC : 0.f;
    Q4 = in ? Q4*SC : 0.f;
    __syncthreads();                                // pk free now
    float* qs = (float*)&pk[0][0];                  // [4][16][17] padded
    qs[(0*16 + lx)*17 + ly] = Q1;
    qs[(1*16 + lx)*17 + ly] = Q2;
    qs[(2*16 + lx)*17 + ly] = Q3;
    qs[(3*16 + lx)*17 + ly] = Q4;
    __syncthreads();
    float o1 = qs[(0*16 + ly)*17 + lx];
    float o2 = qs[(1*16 + ly)*17 + lx];
    float o3 = qs[(2*16 + ly)*17 + lx];
    float o4 = qs[(3*16 + ly)*17 + lx];
    int r1 = tx + ly, r2 = 511 - r1;
    int c1 = ty + lx, c2 = 511 - c1;
    ob[(size_t)r1*DET + c1] = o1;
    ob[(size_t)r2*DET + c1] = o2;
    ob[(size_t)r2*DET + c2] = o3;
    ob[(size_t)r1*DET + c2] = o4;
  }
}

extern "C" void kernel_launch(void* const* d_in, const int* in_sizes, int n_in,
                              void* d_out, int out_size, void* d_ws, size_t ws_size,
                              hipStream_t stream) {
  (void)in_sizes; (void)n_in; (void)out_size; (void)ws_size;
  const float* x = (const float*)d_in[0];
  float* out = (float*)d_out;
  char*  wsb = (char*)d_ws;

  filter_kernel<<<dim3(12, 16, 4), 256, 0, stream>>>(x, wsb);
  backproj_kernel<<<dim3(NBX * NB), 256, 0, stream>>>(wsb, out);
}

// Round 14
// 140.059 us; speedup vs baseline: 1.0432x; 1.0432x over previous
//
#include <hip/hip_runtime.h>
#include <math.h>

#define DET 512
#define NB  16
#define NT  180
#define PI_D 3.14159265358979323846
#define NPAIR 89
#define PADQ 108
#define NGP  45                  // pair-rows gp=0..44 (col gp | col 88-gp)
#define NENT 768                 // 16B entries per pair-row
#define ROWB 12288               // bytes per pair-row (768 x 16)
#define NOFF 101                 // off-diagonal transpose-pair units (a < bt)
#define NMRG 6                   // merged-diagonal blocks (2 diagonals each)
#define NBX  108                 // 101 off-diag + 6 merged-diag + 1 zeroer

// ws layout (bytes):
//   [XF0,+32K)     xf0[b][512]  f32   filtered row t=0
//   [XF90,+32K)    xf90[b][512] f32   filtered row t=90
//   [PK,+8.9M)     pkq[b][gp][768] uint4 entries:
//                  {Tft2[i],Tfu2[i],Uft2[i],Ufu2[i]}, each dword = f16 pair
//                  {v[i], v[i+1]} — pre-paired for v_dot2_f32_f16.
#define TT_OFF   8192
#define XF0_OFF  (TT_OFF + 512*512*2)
#define XF90_OFF (XF0_OFF + 32768)
#define PK_OFF   (XF90_OFF + 32768)

typedef _Float16 half8  __attribute__((ext_vector_type(8)));
typedef _Float16 half4v __attribute__((ext_vector_type(4)));
typedef _Float16 half2v __attribute__((ext_vector_type(2)));
typedef float    float4v __attribute__((ext_vector_type(4)));

__device__ inline half2v H2(unsigned u) { half2v h; __builtin_memcpy(&h, &u, 4); return h; }
__device__ inline half2v pkrtz(float a, float b) {
  auto r = __builtin_amdgcn_cvt_pkrtz(a, b);     // __fp16 vec2 -> bit-cast
  half2v h; __builtin_memcpy(&h, &r, 4); return h;
}
__device__ inline float fdot2f(half2v a, half2v b, float c) {
  return __builtin_amdgcn_fdot2(a, b, c, false);   // 2 f16 FMAs / slot, f32 acc
}
__device__ inline unsigned PK2(float a, float b) {   // RNE f16 pair -> dword
  half2v h; h.x = (_Float16)a; h.y = (_Float16)b;
  unsigned u; __builtin_memcpy(&u, &h, 4); return u;
}

// ---------------- Filter (MFMA GEMM) + pre-paired f16 packing ----------------
// R14: pack rebuilt — threads read neighbor values from xfs LDS and write FULL
// uint2 entries (was 8-16 scattered 2B stores in R13, +10µs). Boundary bytes
// (entry hi at dt-block edges) keep the 2B-store trick; byte union identical
// to R13 -> pkq content bit-identical.
__global__ __launch_bounds__(256) void filter_kernel(const float* __restrict__ x,
                                                     char* __restrict__ wsb) {
  __shared__ _Float16 xs_h[16][512];
  __shared__ _Float16 xs_l[16][512];
  __shared__ float xfs[16][65];
  __shared__ _Float16 wls[8][1032];      // Toeplitz shift-copies (R8)
  char* pkb = wsb + PK_OFF;

  int tid = threadIdx.x;
  int p = blockIdx.x, b = blockIdx.y;
  int dt0 = blockIdx.z * 2;

  // ---- Toeplitz shift-copies ----
  {
    int k0 = tid * 4;
    const float CSC = (float)(-2048.0 / (PI_D * PI_D));
#pragma unroll
    for (int r = 0; r < 8; r++) {
      half4v v;
#pragma unroll
      for (int j = 0; j < 4; j++) {
        int delta = 511 - (k0 + j) - r;
        float wv;
        if (delta == 0) wv = 512.0f;
        else if (delta & 1) wv = CSC / (float)(delta * delta);
        else wv = 0.0f;
        v[j] = (_Float16)wv;
      }
      *(half4v*)&wls[r][k0] = v;
    }
  }

  int m = tid & 15, kp = tid >> 4;
  int tS;
  if (p < 11) tS = (m < 8) ? (8 * p + 1 + m) : (164 - 8 * p + m);
  else        tS = (m == 0) ? 89 : ((m == 1) ? 91 : ((m == 3) ? 90 : 0));
  const float* xb = x + (size_t)b * DET * NT + tS;
#pragma unroll 8
  for (int pass = 0; pass < 16; pass++) {
    int k = pass * 32 + kp * 2;
    int c = k >> 3, h = k & 7;
    int phys = (((c ^ (m & 7)) << 3) | h);
    float v0 = xb[(size_t)k * NT];
    float v1 = xb[(size_t)(k + 1) * NT];
    _Float16 h0 = (_Float16)v0, h1 = (_Float16)v1;
    half2v hh = {h0, h1};
    half2v ll = {(_Float16)(v0 - (float)h0), (_Float16)(v1 - (float)h1)};
    *(half2v*)&xs_h[m][phys] = hh;
    *(half2v*)&xs_l[m][phys] = ll;
  }
  __syncthreads();   // covers xs staging AND wls fill

  int nprb = (p < 11) ? 8 : 1;
  int tpb0 = (p < 11) ? 8 * p : 88;
  if (blockIdx.z == 0) {
    // zero pads. Full 16B: entries [0,107) and [620,768). Partial (2B stores,
    // disjoint from pack's byte positions): entry 107 lo-halves, 619 hi-halves.
    for (int pr = 0; pr < nprb; pr++) {
      int tq = (p < 11) ? (tpb0 + pr) : 88;
      int gp = (tq <= 44) ? tq : 88 - tq;
      char* base = pkb + ((size_t)b * NGP + gp) * ROWB;
      if (tid < 107) {
        uint4 z4 = {0u, 0u, 0u, 0u};
        *(uint4*)(base + (size_t)tid * 16) = z4;
      } else if (tid < 255) {
        uint4 z4 = {0u, 0u, 0u, 0u};
        *(uint4*)(base + (size_t)(620 + tid - 107) * 16) = z4;
      } else {
        unsigned short z = 0;
        *(unsigned short*)(base + 107*16 + 0)  = z; *(unsigned short*)(base + 107*16 + 4)  = z;
        *(unsigned short*)(base + 107*16 + 8)  = z; *(unsigned short*)(base + 107*16 + 12) = z;
        *(unsigned short*)(base + 619*16 + 2)  = z; *(unsigned short*)(base + 619*16 + 6)  = z;
        *(unsigned short*)(base + 619*16 + 10) = z; *(unsigned short*)(base + 619*16 + 14) = z;
      }
    }
  }

  int lane = tid & 63, wv = tid >> 6;
  int mm = lane & 15, q = lane >> 4;
  const _Float16* arh = &xs_h[mm][0];
  const _Float16* arl = &xs_l[mm][0];
  int e = mm & 7;
  int mp = tid >> 5, cc = (tid & 31) * 2;
  int rT = (p < 11) ? mp : 0;
  int rU = (p < 11) ? (15 - mp) : 1;
  int tpp = (p < 11) ? (8 * p + mp) : 88;
  bool dopack = (p < 11) || (mp == 0);
  int gp_  = (tpp <= 44) ? tpp : 88 - tpp;
  int so   = (tpp <= 44) ? 0 : 8;        // T dwords at +0/+4, U at +8/+12

  for (int dti = 0; dti < 2; dti++) {
    int dt = dt0 + dti;
    int dw = dt * 64 + wv * 16 + mm;
    int sdw = 511 - dw;
    const _Float16* thl = &wls[sdw & 7][sdw & ~7];
    float4v acc0 = {0.f, 0.f, 0.f, 0.f};
    float4v acc1 = {0.f, 0.f, 0.f, 0.f};
#pragma unroll 4
    for (int kc = 0; kc < 512; kc += 32) {
      int ph = ((((kc >> 3) + q) ^ e) << 3);
      half8 Ah = *(const half8*)&arh[ph];
      half8 Al = *(const half8*)&arl[ph];
      half8 Bh = *(const half8*)&thl[kc + q * 8];
      acc0 = __builtin_amdgcn_mfma_f32_16x16x32_f16(Ah, Bh, acc0, 0, 0, 0);
      acc1 = __builtin_amdgcn_mfma_f32_16x16x32_f16(Al, Bh, acc1, 0, 0, 0);
    }
    if (dti > 0) __syncthreads();
#pragma unroll
    for (int i = 0; i < 4; i++)
      xfs[q * 4 + i][wv * 16 + mm] = (acc0[i] + acc1[i]) * 0.0009765625f;
    __syncthreads();
    if (dopack) {
      char* base = pkb + ((size_t)b * NGP + gp_) * ROWB;
      float ft0 = xfs[rT][cc], ft1 = xfs[rT][cc + 1];
      float fu0 = xfs[rU][cc], fu1 = xfs[rU][cc + 1];
      int en = PADQ + dt * 64 + cc;
      uint2 e0; e0.x = PK2(ft0, ft1); e0.y = PK2(fu0, fu1);
      *(uint2*)(base + (size_t)en * 16 + so) = e0;
      if (tpp == 44) *(uint2*)(base + (size_t)en * 16 + 8) = e0;
      if (cc < 62) {
        float ft2 = xfs[rT][cc + 2], fu2 = xfs[rU][cc + 2];
        uint2 e1; e1.x = PK2(ft1, ft2); e1.y = PK2(fu1, fu2);
        *(uint2*)(base + (size_t)(en + 1) * 16 + so) = e1;
        if (tpp == 44) *(uint2*)(base + (size_t)(en + 1) * 16 + 8) = e1;
      } else {
        // entry 63 of this dt: lo halves only (hi = next dt's col0 writer)
        _Float16 h1 = (_Float16)ft1, g1 = (_Float16)fu1;
        *(_Float16*)(base + (size_t)(en + 1) * 16 + 0 + so) = h1;
        *(_Float16*)(base + (size_t)(en + 1) * 16 + 4 + so) = g1;
        if (tpp == 44) {
          *(_Float16*)(base + (size_t)(en + 1) * 16 + 8)  = h1;
          *(_Float16*)(base + (size_t)(en + 1) * 16 + 12) = g1;
        }
      }
      if (cc == 0) {
        // hi halves of previous entry (pair {v[-1], v[0]} of this dt)
        _Float16 h0 = (_Float16)ft0, g0 = (_Float16)fu0;
        *(_Float16*)(base + (size_t)(en - 1) * 16 + 2 + so) = h0;
        *(_Float16*)(base + (size_t)(en - 1) * 16 + 6 + so) = g0;
        if (tpp == 44) {
          *(_Float16*)(base + (size_t)(en - 1) * 16 + 10) = h0;
          *(_Float16*)(base + (size_t)(en - 1) * 16 + 14) = g0;
        }
      }
    }
    if (p == 11 && tid < 64) {         // singles: row2=t0, row3=t90
      float* f0  = (float*)(wsb + XF0_OFF)  + (size_t)b * DET;
      float* f90 = (float*)(wsb + XF90_OFF) + (size_t)b * DET;
      f0[dt * 64 + tid]  = xfs[2][tid];
      f90[dt * 64 + tid] = xfs[3][tid];
    }
  }
}

// ---------------- Backprojection v17: fdot2 + pre-paired entries (R13, unchanged) ----------------
#define XTRACT(nm, qq, SW)                                                     \
  half2v Tft##nm = H2(SW ? qq.z : qq.x), Tfu##nm = H2(SW ? qq.w : qq.y);       \
  half2v Uft##nm = H2(SW ? qq.x : qq.z), Ufu##nm = H2(SW ? qq.y : qq.w);

#define PROCESS(c_, s_, SW)                                                    \
  {                                                                            \
    float inner = fmaf(-(s_), q_, 363.5f);                                     \
    float iyA = fmaf( (c_), p_, inner);                                        \
    float iyB = fmaf(-(c_), p_, inner);                                        \
    int   iA = (int)iyA;  float wA = __builtin_amdgcn_fractf(iyA);             \
    int   iB = (int)iyB;  float wB = __builtin_amdgcn_fractf(iyB);             \
    half2v wpA = pkrtz(1.f - wA, wA);                                          \
    half2v wpAr = pkrtz(wA, 1.f - wA);                                         \
    half2v wpB = pkrtz(1.f - wB, wB);                                          \
    half2v wpBr = pkrtz(wB, 1.f - wB);                                         \
    uint4 qA = colI[iA], qB = colI[iB];                                        \
    uint4 qMA = colI[726 - iA], qMB = colI[726 - iB];                          \
    XTRACT(A, qA, SW)  XTRACT(B, qB, SW)                                       \
    XTRACT(MA, qMA, SW) XTRACT(MB, qMB, SW)                                    \
    A1 = fdot2f(wpA, TftA, A1);   A1 = fdot2f(wpB, TfuB, A1);                  \
    A2 = fdot2f(wpB, TftB, A2);   A2 = fdot2f(wpA, TfuA, A2);                  \
    A3 = fdot2f(wpAr, TftMA, A3); A3 = fdot2f(wpBr, TfuMB, A3);                \
    A4 = fdot2f(wpBr, TftMB, A4); A4 = fdot2f(wpAr, TfuMA, A4);                \
    B1 = fdot2f(wpAr, UftMA, B1); B1 = fdot2f(wpB, UfuB, B1);                  \
    B2 = fdot2f(wpBr, UftMB, B2); B2 = fdot2f(wpA, UfuA, B2);                  \
    B3 = fdot2f(wpA, UftA, B3);   B3 = fdot2f(wpBr, UfuMB, B3);                \
    B4 = fdot2f(wpB, UftB, B4);   B4 = fdot2f(wpAr, UfuMA, B4);                \
  }

#define PROCESSP(c_, s_, SW, pp, qq_, AA1, AA2, AA3, AA4)                      \
  {                                                                            \
    float inner = fmaf(-(s_), (qq_), 363.5f);                                  \
    float iyA = fmaf( (c_), (pp), inner);                                      \
    float iyB = fmaf(-(c_), (pp), inner);                                      \
    int   iA = (int)iyA;  float wA = __builtin_amdgcn_fractf(iyA);             \
    int   iB = (int)iyB;  float wB = __builtin_amdgcn_fractf(iyB);             \
    half2v wpA = pkrtz(1.f - wA, wA);                                          \
    half2v wpAr = pkrtz(wA, 1.f - wA);                                         \
    half2v wpB = pkrtz(1.f - wB, wB);                                          \
    half2v wpBr = pkrtz(wB, 1.f - wB);                                         \
    uint4 qA = colI[iA], qB = colI[iB];                                        \
    uint4 qMA = colI[726 - iA], qMB = colI[726 - iB];                          \
    half2v TftA = H2(SW ? qA.z : qA.x),  TfuA = H2(SW ? qA.w : qA.y);          \
    half2v TftB = H2(SW ? qB.z : qB.x),  TfuB = H2(SW ? qB.w : qB.y);          \
    half2v TftMA = H2(SW ? qMA.z : qMA.x), TfuMA = H2(SW ? qMA.w : qMA.y);     \
    half2v TftMB = H2(SW ? qMB.z : qMB.x), TfuMB = H2(SW ? qMB.w : qMB.y);     \
    AA1 = fdot2f(wpA, TftA, AA1);   AA1 = fdot2f(wpB, TfuB, AA1);              \
    AA2 = fdot2f(wpB, TftB, AA2);   AA2 = fdot2f(wpA, TfuA, AA2);              \
    AA3 = fdot2f(wpAr, TftMA, AA3); AA3 = fdot2f(wpBr, TfuMB, AA3);            \
    AA4 = fdot2f(wpBr, TftMB, AA4); AA4 = fdot2f(wpAr, TfuMA, AA4);            \
  }

__global__ __launch_bounds__(256, 6) void backproj_kernel(
    const char* __restrict__ wsb, float* __restrict__ out) {
  __shared__ uint4 pk[2][NENT];     // 24576 B double-buffer
  __shared__ float2 trigs[48];
  int tid = threadIdx.x;
  // batch-pair XCD swizzle: XCD = f%8 serves b in {2k,2k+1}
  int f = blockIdx.x;
  int sub = f & 15;
  int b = 2 * (sub & 7) + (sub >> 3);
  int bx = f >> 4;                  // unit 0..107
  int lx = tid & 15, ly = tid >> 4;
  float* ob = out + (size_t)b * DET * DET;
  int w = tid >> 6, l = tid & 63;

  if (bx == NBX - 1) {
    // zero dead 16x16 tiles (a, bt<L[a]) and their 3 mirrors
    const int LDEAD[10] = {10,8,6,5,4,3,2,2,1,1};
    for (int a = 0; a < 10; a++)
      for (int bt = 0; bt < LDEAD[a]; bt++) {
        int X1 = 16*a + lx, X2 = 511 - X1;
        int Y1 = 16*bt + ly, Y2 = 511 - Y1;
        ob[(size_t)Y1*DET + X1] = 0.f;
        ob[(size_t)Y1*DET + X2] = 0.f;
        ob[(size_t)Y2*DET + X1] = 0.f;
        ob[(size_t)Y2*DET + X2] = 0.f;
      }
    return;
  }

  // pair trig: (cos t, sin t), t = tid+1 degrees
  if (tid < NGP) {
    float th = (float)(tid + 1) * (float)(PI_D / 180.0);
    float2 cs; cs.x = cosf(th); cs.y = sinf(th);
    trigs[tid] = cs;
  }

  const char* pkgb = wsb + PK_OFF + (size_t)b * NGP * ROWB;

  // stage pair-row g (12288 B): 12 chunks of 1024B, 3 per wave (16B/lane DMA)
  auto stage_group = [&](int g, int par) {
#pragma unroll
    for (int i = 0; i < 3; i++) {
      int c = w + 4 * i;
      const char* src = pkgb + (size_t)g * ROWB + c * 1024 + l * 16;
      char* dst = (char*)&pk[par][0] + c * 1024;
      __builtin_amdgcn_global_load_lds(
          (const __attribute__((address_space(1))) unsigned int*)src,
          (__attribute__((address_space(3))) unsigned int*)dst, 16, 0, 0);
    }
  };

  const float* f0  = (const float*)(wsb + XF0_OFF)  + (size_t)b * DET;
  const float* f90 = (const float*)(wsb + XF90_OFF) + (size_t)b * DET;
  const float SC = (float)(PI_D / 360.0);

  if (bx >= NOFF) {
    // ---- merged-diagonal block: two diagonal tiles, P-only ----
    int d = bx - NOFF;
    int a1 = 4 + 2 * d, a2 = 5 + 2 * d;
    float p1_ = (float)(16 * a1 + lx) - 255.5f, q1_ = (float)(16 * a1 + ly) - 255.5f;
    float p2_ = (float)(16 * a2 + lx) - 255.5f, q2_ = (float)(16 * a2 + ly) - 255.5f;
    int mk1 = 481 - 32 * a1, mn1 = 505 - 32 * a1 - 8 * w;
    int mk2 = 481 - 32 * a2, mn2 = 505 - 32 * a2 - 8 * w;
    bool wl1 = (mk1 * mk1 + mn1 * mn1 <= 261632);
    bool wl2 = (mk2 * mk2 + mn2 * mn2 <= 261632);

    float A1=0.f, A2=0.f, A3=0.f, A4=0.f;
    float C1=0.f, C2=0.f, C3=0.f, C4=0.f;

    stage_group(0, 0);
    __syncthreads();
    for (int g = 0; g < NGP; g++) {
      if (g + 1 < NGP) stage_group(g + 1, (g + 1) & 1);
      float2 cs = trigs[g];
      const uint4* colI = &pk[g & 1][0];
      if (wl1) {
        PROCESSP(cs.x, cs.y, 0, p1_, q1_, A1, A2, A3, A4);
        if (g != 44) PROCESSP(cs.y, cs.x, 1, p1_, q1_, A1, A2, A3, A4);
      }
      if (wl2) {
        PROCESSP(cs.x, cs.y, 0, p2_, q2_, C1, C2, C3, C4);
        if (g != 44) PROCESSP(cs.y, cs.x, 1, p2_, q2_, C1, C2, C3, C4);
      }
      __syncthreads();
    }
#pragma unroll
    for (int t = 0; t < 2; t++) {
      int a = t ? a2 : a1;
      int X1 = 16 * a + lx, X2 = 511 - X1;
      int Y1 = 16 * a + ly, Y2 = 511 - Y1;
      int kx = 2 * X1 - 511, ky = 2 * Y1 - 511;
      bool in = (kx * kx + ky * ky) <= 261632;
      float g0x1 = f0[X1], g0x2 = f0[X2];
      float g90y1 = f90[Y1], g90y2 = f90[Y2];
      float P1 = (t ? C1 : A1) + g0x1 + g90y2;
      float P2 = (t ? C2 : A2) + g0x2 + g90y2;
      float P3 = (t ? C3 : A3) + g0x2 + g90y1;
      float P4 = (t ? C4 : A4) + g0x1 + g90y1;
      ob[(size_t)Y1 * DET + X1] = in ? P1 * SC : 0.f;
      ob[(size_t)Y1 * DET + X2] = in ? P2 * SC : 0.f;
      ob[(size_t)Y2 * DET + X2] = in ? P3 * SC : 0.f;
      ob[(size_t)Y2 * DET + X1] = in ? P4 * SC : 0.f;
    }
    return;
  }

  // ---- off-diagonal unit (a < bt): P-quad + transposed Q-quad ----
  int a = (bx>=6)+(bx>=14)+(bx>=24)+(bx>=35)+(bx>=46)+(bx>=56)+(bx>=65)
        + (bx>=73)+(bx>=80)+(bx>=86)+(bx>=91)+(bx>=95)+(bx>=98)+(bx>=100);
  int Sa, bs;
  if (a < 8) { Sa = (int)((0x41382E23180E0600ULL >> (8*a)) & 0xFF);
               bs = (int)((0x080706050506080AULL >> (8*a)) & 0xFF); }
  else       { Sa = (int)((0x0064625F5B565049ULL >> (8*(a-8))) & 0xFF);
               bs = (int)((0x000F0E0D0C0B0A09ULL >> (8*(a-8))) & 0xFF); }
  int bt = bx - Sa + bs;
  int tx = 16*a, ty = 16*bt;

  int X1 = tx + lx, X2 = 511 - X1;
  int Y1 = ty + ly, Y2 = 511 - Y1;
  float p_ = (float)X1 - 255.5f;
  float q_ = (float)Y1 - 255.5f;

  int mkx = 481 - 32*a;
  int mky = 505 - 32*bt - 8*w;
  bool wlive = (mkx*mkx + mky*mky <= 261632);

  float A1=0.f, A2=0.f, A3=0.f, A4=0.f;   // P-tile mirrors
  float B1=0.f, B2=0.f, B3=0.f, B4=0.f;   // Q (transposed) tile mirrors

  stage_group(0, 0);
  __syncthreads();   // covers stage(0) AND trigs fill

  for (int g = 0; g < NGP; g++) {
    if (g + 1 < NGP) stage_group(g + 1, (g + 1) & 1);
    float2 cs = trigs[g];
    const uint4* colI = &pk[g & 1][0];
    if (wlive) {
      PROCESS(cs.x, cs.y, 0);                    // tp = g
      if (g != 44) PROCESS(cs.y, cs.x, 1);       // tp = 88-g
    }
    __syncthreads();
  }

  // epilogue: singles t=0 / t=90, mask, scale
  int kx = 2*X1 - 511, ky = 2*Y1 - 511;
  bool in = (kx*kx + ky*ky) <= 261632;

  float g0x1 = f0[X1], g0x2 = f0[X2];
  float g90y1 = f90[Y1], g90y2 = f90[Y2];
  float P1 = A1 + g0x1 + g90y2;
  float P2 = A2 + g0x2 + g90y2;
  float P3 = A3 + g0x2 + g90y1;
  float P4 = A4 + g0x1 + g90y1;
  ob[(size_t)Y1*DET + X1] = in ? P1*SC : 0.f;
  ob[(size_t)Y1*DET + X2] = in ? P2*SC : 0.f;
  ob[(size_t)Y2*DET + X2] = in ? P3*SC : 0.f;
  ob[(size_t)Y2*DET + X1] = in ? P4*SC : 0.f;

  {
    float g0y1 = f0[Y1], g0y2 = f0[Y2];
    float g90x1 = f90[X1], g90x2 = f90[X2];
    float Q1 = B1 + g0y1 + g90x2;
    float Q2 = B2 + g0y1 + g90x1;
    float Q3 = B3 + g0y2 + g90x1;
    float Q4 = B4 + g0y2 + g90x2;
    Q1 = in ? Q1*SC : 0.f;
    Q2 = in ? Q2*SC : 0.f;
    Q3 = in ? Q3*SC : 0.f;
    Q4 = in ? Q4*SC : 0.f;
    __syncthreads();                                // pk free now
    float* qs = (float*)&pk[0][0];                  // [4][16][17] padded
    qs[(0*16 + lx)*17 + ly] = Q1;
    qs[(1*16 + lx)*17 + ly] = Q2;
    qs[(2*16 + lx)*17 + ly] = Q3;
    qs[(3*16 + lx)*17 + ly] = Q4;
    __syncthreads();
    float o1 = qs[(0*16 + ly)*17 + lx];
    float o2 = qs[(1*16 + ly)*17 + lx];
    float o3 = qs[(2*16 + ly)*17 + lx];
    float o4 = qs[(3*16 + ly)*17 + lx];
    int r1 = tx + ly, r2 = 511 - r1;
    int c1 = ty + lx, c2 = 511 - c1;
    ob[(size_t)r1*DET + c1] = o1;
    ob[(size_t)r2*DET + c1] = o2;
    ob[(size_t)r2*DET + c2] = o3;
    ob[(size_t)r1*DET + c2] = o4;
  }
}

extern "C" void kernel_launch(void* const* d_in, const int* in_sizes, int n_in,
                              void* d_out, int out_size, void* d_ws, size_t ws_size,
                              hipStream_t stream) {
  (void)in_sizes; (void)n_in; (void)out_size; (void)ws_size;
  const float* x = (const float*)d_in[0];
  float* out = (float*)d_out;
  char*  wsb = (char*)d_ws;

  filter_kernel<<<dim3(12, 16, 4), 256, 0, stream>>>(x, wsb);
  backproj_kernel<<<dim3(NBX * NB), 256, 0, stream>>>(wsb, out);
}

// Round 15
// 137.291 us; speedup vs baseline: 1.0642x; 1.0202x over previous
//
#include <hip/hip_runtime.h>
#include <math.h>

#define DET 512
#define NB  16
#define NT  180
#define PI_D 3.14159265358979323846
#define NPAIR 89
#define NGP  45                  // pair-rows gp=0..44 (col gp | col 88-gp)
#define NENT 516                 // 16B entries per pair-row (old entries 104..619)
#define ROWB 8256                // bytes per pair-row (516 x 16)
#define NOFF 101                 // off-diagonal transpose-pair units (a < bt)
#define NMRG 6                   // merged-diagonal blocks (2 diagonals each)
#define NBX  108                 // 101 off-diag + 6 merged-diag + 1 zeroer

// ws layout (bytes):
//   [XF0,+32K)     xf0[b][512]  f32   filtered row t=0
//   [XF90,+32K)    xf90[b][512] f32   filtered row t=90
//   [PK,+5.9M)     pkq[b][gp][516] uint4 entries (old det-index j = entry+104):
//                  {Tft2,Tfu2,Uft2,Ufu2}, each dword = f16 pair {v[j],v[j+1]}
//                  pre-paired for v_dot2_f32_f16. In-circle reads span entries
//                  [3,515]; out-of-circle threads are med3-clamped (masked later).
#define TT_OFF   8192
#define XF0_OFF  (TT_OFF + 512*512*2)
#define XF90_OFF (XF0_OFF + 32768)
#define PK_OFF   (XF90_OFF + 32768)

typedef _Float16 half8  __attribute__((ext_vector_type(8)));
typedef _Float16 half4v __attribute__((ext_vector_type(4)));
typedef _Float16 half2v __attribute__((ext_vector_type(2)));
typedef float    float4v __attribute__((ext_vector_type(4)));

__device__ inline half2v H2(unsigned u) { half2v h; __builtin_memcpy(&h, &u, 4); return h; }
__device__ inline half2v pkrtz(float a, float b) {
  auto r = __builtin_amdgcn_cvt_pkrtz(a, b);     // __fp16 vec2 -> bit-cast
  half2v h; __builtin_memcpy(&h, &r, 4); return h;
}
__device__ inline float fdot2f(half2v a, half2v b, float c) {
  return __builtin_amdgcn_fdot2(a, b, c, false);   // 2 f16 FMAs / slot, f32 acc
}
__device__ inline unsigned PK2(float a, float b) {   // RNE f16 pair -> dword
  half2v h; h.x = (_Float16)a; h.y = (_Float16)b;
  unsigned u; __builtin_memcpy(&u, &h, 4); return u;
}
__device__ inline int clamp3_515(int i) {            // v_med3_i32
  return min(max(i, 3), 515);
}

// ---------------- Filter (MFMA GEMM) + pre-paired f16 packing ----------------
// R15: row shrunk 768->516 entries (pads removed; backproj clamps). Pack base
// shift: entry = 4 + dt*64 + cc (old - 104). Zero pass reduced to 16 boundary
// bytes per row (entry 3 lo-halves = v107, entry 515 hi-halves = v620).
__global__ __launch_bounds__(256) void filter_kernel(const float* __restrict__ x,
                                                     char* __restrict__ wsb) {
  __shared__ _Float16 xs_h[16][512];
  __shared__ _Float16 xs_l[16][512];
  __shared__ float xfs[16][65];
  __shared__ _Float16 wls[8][1032];      // Toeplitz shift-copies (R8)
  char* pkb = wsb + PK_OFF;

  int tid = threadIdx.x;
  int p = blockIdx.x, b = blockIdx.y;
  int dt0 = blockIdx.z * 2;

  // ---- Toeplitz shift-copies ----
  {
    int k0 = tid * 4;
    const float CSC = (float)(-2048.0 / (PI_D * PI_D));
#pragma unroll
    for (int r = 0; r < 8; r++) {
      half4v v;
#pragma unroll
      for (int j = 0; j < 4; j++) {
        int delta = 511 - (k0 + j) - r;
        float wv;
        if (delta == 0) wv = 512.0f;
        else if (delta & 1) wv = CSC / (float)(delta * delta);
        else wv = 0.0f;
        v[j] = (_Float16)wv;
      }
      *(half4v*)&wls[r][k0] = v;
    }
  }

  int m = tid & 15, kp = tid >> 4;
  int tS;
  if (p < 11) tS = (m < 8) ? (8 * p + 1 + m) : (164 - 8 * p + m);
  else        tS = (m == 0) ? 89 : ((m == 1) ? 91 : ((m == 3) ? 90 : 0));
  const float* xb = x + (size_t)b * DET * NT + tS;
#pragma unroll 8
  for (int pass = 0; pass < 16; pass++) {
    int k = pass * 32 + kp * 2;
    int c = k >> 3, h = k & 7;
    int phys = (((c ^ (m & 7)) << 3) | h);
    float v0 = xb[(size_t)k * NT];
    float v1 = xb[(size_t)(k + 1) * NT];
    _Float16 h0 = (_Float16)v0, h1 = (_Float16)v1;
    half2v hh = {h0, h1};
    half2v ll = {(_Float16)(v0 - (float)h0), (_Float16)(v1 - (float)h1)};
    *(half2v*)&xs_h[m][phys] = hh;
    *(half2v*)&xs_l[m][phys] = ll;
  }
  __syncthreads();   // covers xs staging AND wls fill

  int nprb = (p < 11) ? 8 : 1;
  int tpb0 = (p < 11) ? 8 * p : 88;
  if (blockIdx.z == 0 && tid == 0) {
    // boundary zeros only: entry 3 lo-halves (v107=0), entry 515 hi (v620=0)
    for (int pr = 0; pr < nprb; pr++) {
      int tq = (p < 11) ? (tpb0 + pr) : 88;
      int gp = (tq <= 44) ? tq : 88 - tq;
      char* base = pkb + ((size_t)b * NGP + gp) * ROWB;
      unsigned short z = 0;
      *(unsigned short*)(base + 3*16 + 0)  = z; *(unsigned short*)(base + 3*16 + 4)  = z;
      *(unsigned short*)(base + 3*16 + 8)  = z; *(unsigned short*)(base + 3*16 + 12) = z;
      *(unsigned short*)(base + 515*16 + 2)  = z; *(unsigned short*)(base + 515*16 + 6)  = z;
      *(unsigned short*)(base + 515*16 + 10) = z; *(unsigned short*)(base + 515*16 + 14) = z;
    }
  }

  int lane = tid & 63, wv = tid >> 6;
  int mm = lane & 15, q = lane >> 4;
  const _Float16* arh = &xs_h[mm][0];
  const _Float16* arl = &xs_l[mm][0];
  int e = mm & 7;
  int mp = tid >> 5, cc = (tid & 31) * 2;
  int rT = (p < 11) ? mp : 0;
  int rU = (p < 11) ? (15 - mp) : 1;
  int tpp = (p < 11) ? (8 * p + mp) : 88;
  bool dopack = (p < 11) || (mp == 0);
  int gp_  = (tpp <= 44) ? tpp : 88 - tpp;
  int so   = (tpp <= 44) ? 0 : 8;        // T dwords at +0/+4, U at +8/+12

  for (int dti = 0; dti < 2; dti++) {
    int dt = dt0 + dti;
    int dw = dt * 64 + wv * 16 + mm;
    int sdw = 511 - dw;
    const _Float16* thl = &wls[sdw & 7][sdw & ~7];
    float4v acc0 = {0.f, 0.f, 0.f, 0.f};
    float4v acc1 = {0.f, 0.f, 0.f, 0.f};
#pragma unroll 4
    for (int kc = 0; kc < 512; kc += 32) {
      int ph = ((((kc >> 3) + q) ^ e) << 3);
      half8 Ah = *(const half8*)&arh[ph];
      half8 Al = *(const half8*)&arl[ph];
      half8 Bh = *(const half8*)&thl[kc + q * 8];
      acc0 = __builtin_amdgcn_mfma_f32_16x16x32_f16(Ah, Bh, acc0, 0, 0, 0);
      acc1 = __builtin_amdgcn_mfma_f32_16x16x32_f16(Al, Bh, acc1, 0, 0, 0);
    }
    if (dti > 0) __syncthreads();
#pragma unroll
    for (int i = 0; i < 4; i++)
      xfs[q * 4 + i][wv * 16 + mm] = (acc0[i] + acc1[i]) * 0.0009765625f;
    __syncthreads();
    if (dopack) {
      char* base = pkb + ((size_t)b * NGP + gp_) * ROWB;
      float ft0 = xfs[rT][cc], ft1 = xfs[rT][cc + 1];
      float fu0 = xfs[rU][cc], fu1 = xfs[rU][cc + 1];
      int en = 4 + dt * 64 + cc;          // new base: old entry - 104
      uint2 e0; e0.x = PK2(ft0, ft1); e0.y = PK2(fu0, fu1);
      *(uint2*)(base + (size_t)en * 16 + so) = e0;
      if (tpp == 44) *(uint2*)(base + (size_t)en * 16 + 8) = e0;
      if (cc < 62) {
        float ft2 = xfs[rT][cc + 2], fu2 = xfs[rU][cc + 2];
        uint2 e1; e1.x = PK2(ft1, ft2); e1.y = PK2(fu1, fu2);
        *(uint2*)(base + (size_t)(en + 1) * 16 + so) = e1;
        if (tpp == 44) *(uint2*)(base + (size_t)(en + 1) * 16 + 8) = e1;
      } else {
        // entry 67+64dt: lo halves only (hi = next dt's col0 writer)
        _Float16 h1 = (_Float16)ft1, g1 = (_Float16)fu1;
        *(_Float16*)(base + (size_t)(en + 1) * 16 + 0 + so) = h1;
        *(_Float16*)(base + (size_t)(en + 1) * 16 + 4 + so) = g1;
        if (tpp == 44) {
          *(_Float16*)(base + (size_t)(en + 1) * 16 + 8)  = h1;
          *(_Float16*)(base + (size_t)(en + 1) * 16 + 12) = g1;
        }
      }
      if (cc == 0) {
        // hi halves of previous entry (pair {v[-1], v[0]} of this dt)
        _Float16 h0 = (_Float16)ft0, g0 = (_Float16)fu0;
        *(_Float16*)(base + (size_t)(en - 1) * 16 + 2 + so) = h0;
        *(_Float16*)(base + (size_t)(en - 1) * 16 + 6 + so) = g0;
        if (tpp == 44) {
          *(_Float16*)(base + (size_t)(en - 1) * 16 + 10) = h0;
          *(_Float16*)(base + (size_t)(en - 1) * 16 + 14) = g0;
        }
      }
    }
    if (p == 11 && tid < 64) {         // singles: row2=t0, row3=t90
      float* f0  = (float*)(wsb + XF0_OFF)  + (size_t)b * DET;
      float* f90 = (float*)(wsb + XF90_OFF) + (size_t)b * DET;
      f0[dt * 64 + tid]  = xfs[2][tid];
      f90[dt * 64 + tid] = xfs[3][tid];
    }
  }
}

// ---------------- Backprojection v18: clamped 516-entry rows ----------------
// LDS 2x8256 = 16.5KB -> 8 blocks/CU: all 1728 blocks co-resident (no straggler
// round). Index rebased by -104 (inner const 259.5); med3 clamp to [3,515]
// replaces pads (out-of-circle threads read garbage, masked at write). Mirror
// index: 518 - i. Weights (fract) shift-invariant -> in-circle bit-identical.
#define XTRACT(nm, qq, SW)                                                     \
  half2v Tft##nm = H2(SW ? qq.z : qq.x), Tfu##nm = H2(SW ? qq.w : qq.y);       \
  half2v Uft##nm = H2(SW ? qq.x : qq.z), Ufu##nm = H2(SW ? qq.y : qq.w);

#define PROCESS(c_, s_, SW)                                                    \
  {                                                                            \
    float inner = fmaf(-(s_), q_, 259.5f);                                     \
    float iyA = fmaf( (c_), p_, inner);                                        \
    float iyB = fmaf(-(c_), p_, inner);                                        \
    int   iA = clamp3_515((int)iyA);  float wA = __builtin_amdgcn_fractf(iyA); \
    int   iB = clamp3_515((int)iyB);  float wB = __builtin_amdgcn_fractf(iyB); \
    half2v wpA = pkrtz(1.f - wA, wA);                                          \
    half2v wpAr = pkrtz(wA, 1.f - wA);                                         \
    half2v wpB = pkrtz(1.f - wB, wB);                                          \
    half2v wpBr = pkrtz(wB, 1.f - wB);                                         \
    uint4 qA = colI[iA], qB = colI[iB];                                        \
    uint4 qMA = colI[518 - iA], qMB = colI[518 - iB];                          \
    XTRACT(A, qA, SW)  XTRACT(B, qB, SW)                                       \
    XTRACT(MA, qMA, SW) XTRACT(MB, qMB, SW)                                    \
    A1 = fdot2f(wpA, TftA, A1);   A1 = fdot2f(wpB, TfuB, A1);                  \
    A2 = fdot2f(wpB, TftB, A2);   A2 = fdot2f(wpA, TfuA, A2);                  \
    A3 = fdot2f(wpAr, TftMA, A3); A3 = fdot2f(wpBr, TfuMB, A3);                \
    A4 = fdot2f(wpBr, TftMB, A4); A4 = fdot2f(wpAr, TfuMA, A4);                \
    B1 = fdot2f(wpAr, UftMA, B1); B1 = fdot2f(wpB, UfuB, B1);                  \
    B2 = fdot2f(wpBr, UftMB, B2); B2 = fdot2f(wpA, UfuA, B2);                  \
    B3 = fdot2f(wpA, UftA, B3);   B3 = fdot2f(wpBr, UfuMB, B3);                \
    B4 = fdot2f(wpB, UftB, B4);   B4 = fdot2f(wpAr, UfuMA, B4);                \
  }

#define PROCESSP(c_, s_, SW, pp, qq_, AA1, AA2, AA3, AA4)                      \
  {                                                                            \
    float inner = fmaf(-(s_), (qq_), 259.5f);                                  \
    float iyA = fmaf( (c_), (pp), inner);                                      \
    float iyB = fmaf(-(c_), (pp), inner);                                      \
    int   iA = clamp3_515((int)iyA);  float wA = __builtin_amdgcn_fractf(iyA); \
    int   iB = clamp3_515((int)iyB);  float wB = __builtin_amdgcn_fractf(iyB); \
    half2v wpA = pkrtz(1.f - wA, wA);                                          \
    half2v wpAr = pkrtz(wA, 1.f - wA);                                         \
    half2v wpB = pkrtz(1.f - wB, wB);                                          \
    half2v wpBr = pkrtz(wB, 1.f - wB);                                         \
    uint4 qA = colI[iA], qB = colI[iB];                                        \
    uint4 qMA = colI[518 - iA], qMB = colI[518 - iB];                          \
    half2v TftA = H2(SW ? qA.z : qA.x),  TfuA = H2(SW ? qA.w : qA.y);          \
    half2v TftB = H2(SW ? qB.z : qB.x),  TfuB = H2(SW ? qB.w : qB.y);          \
    half2v TftMA = H2(SW ? qMA.z : qMA.x), TfuMA = H2(SW ? qMA.w : qMA.y);     \
    half2v TftMB = H2(SW ? qMB.z : qMB.x), TfuMB = H2(SW ? qMB.w : qMB.y);     \
    AA1 = fdot2f(wpA, TftA, AA1);   AA1 = fdot2f(wpB, TfuB, AA1);              \
    AA2 = fdot2f(wpB, TftB, AA2);   AA2 = fdot2f(wpA, TfuA, AA2);              \
    AA3 = fdot2f(wpAr, TftMA, AA3); AA3 = fdot2f(wpBr, TfuMB, AA3);            \
    AA4 = fdot2f(wpBr, TftMB, AA4); AA4 = fdot2f(wpAr, TfuMA, AA4);            \
  }

__global__ __launch_bounds__(256, 8) void backproj_kernel(
    const char* __restrict__ wsb, float* __restrict__ out) {
  __shared__ uint4 pk[2][NENT];     // 16512 B double-buffer
  __shared__ float2 trigs[48];
  int tid = threadIdx.x;
  // batch-pair XCD swizzle: XCD = f%8 serves b in {2k,2k+1}
  int f = blockIdx.x;
  int sub = f & 15;
  int b = 2 * (sub & 7) + (sub >> 3);
  int bx = f >> 4;                  // unit 0..107
  int lx = tid & 15, ly = tid >> 4;
  float* ob = out + (size_t)b * DET * DET;
  int w = tid >> 6, l = tid & 63;

  if (bx == NBX - 1) {
    // zero dead 16x16 tiles (a, bt<L[a]) and their 3 mirrors
    const int LDEAD[10] = {10,8,6,5,4,3,2,2,1,1};
    for (int a = 0; a < 10; a++)
      for (int bt = 0; bt < LDEAD[a]; bt++) {
        int X1 = 16*a + lx, X2 = 511 - X1;
        int Y1 = 16*bt + ly, Y2 = 511 - Y1;
        ob[(size_t)Y1*DET + X1] = 0.f;
        ob[(size_t)Y1*DET + X2] = 0.f;
        ob[(size_t)Y2*DET + X1] = 0.f;
        ob[(size_t)Y2*DET + X2] = 0.f;
      }
    return;
  }

  // pair trig: (cos t, sin t), t = tid+1 degrees
  if (tid < NGP) {
    float th = (float)(tid + 1) * (float)(PI_D / 180.0);
    float2 cs; cs.x = cosf(th); cs.y = sinf(th);
    trigs[tid] = cs;
  }

  const char* pkgb = wsb + PK_OFF + (size_t)b * NGP * ROWB;

  // stage pair-row g (8256 B): 8 chunks of 1024B (2/wave, 16B/lane DMA)
  // + 64B tail (entries 512..515) via reg copy by 4 threads.
  auto stage_group = [&](int g, int par) {
    const char* src = pkgb + (size_t)g * ROWB;
    char* dst = (char*)&pk[par][0];
#pragma unroll
    for (int i = 0; i < 2; i++) {
      int c = w + 4 * i;
      __builtin_amdgcn_global_load_lds(
          (const __attribute__((address_space(1))) unsigned int*)(src + c * 1024 + l * 16),
          (__attribute__((address_space(3))) unsigned int*)(dst + c * 1024),
          16, 0, 0);
    }
    if (tid < 4) {
      uint4 v = *(const uint4*)(src + 8192 + tid * 16);
      *(uint4*)(dst + 8192 + tid * 16) = v;
    }
  };

  const float* f0  = (const float*)(wsb + XF0_OFF)  + (size_t)b * DET;
  const float* f90 = (const float*)(wsb + XF90_OFF) + (size_t)b * DET;
  const float SC = (float)(PI_D / 360.0);

  if (bx >= NOFF) {
    // ---- merged-diagonal block: two diagonal tiles, P-only ----
    int d = bx - NOFF;
    int a1 = 4 + 2 * d, a2 = 5 + 2 * d;
    float p1_ = (float)(16 * a1 + lx) - 255.5f, q1_ = (float)(16 * a1 + ly) - 255.5f;
    float p2_ = (float)(16 * a2 + lx) - 255.5f, q2_ = (float)(16 * a2 + ly) - 255.5f;
    int mk1 = 481 - 32 * a1, mn1 = 505 - 32 * a1 - 8 * w;
    int mk2 = 481 - 32 * a2, mn2 = 505 - 32 * a2 - 8 * w;
    bool wl1 = (mk1 * mk1 + mn1 * mn1 <= 261632);
    bool wl2 = (mk2 * mk2 + mn2 * mn2 <= 261632);

    float A1=0.f, A2=0.f, A3=0.f, A4=0.f;
    float C1=0.f, C2=0.f, C3=0.f, C4=0.f;

    stage_group(0, 0);
    __syncthreads();
    for (int g = 0; g < NGP; g++) {
      if (g + 1 < NGP) stage_group(g + 1, (g + 1) & 1);
      float2 cs = trigs[g];
      const uint4* colI = &pk[g & 1][0];
      if (wl1) {
        PROCESSP(cs.x, cs.y, 0, p1_, q1_, A1, A2, A3, A4);
        if (g != 44) PROCESSP(cs.y, cs.x, 1, p1_, q1_, A1, A2, A3, A4);
      }
      if (wl2) {
        PROCESSP(cs.x, cs.y, 0, p2_, q2_, C1, C2, C3, C4);
        if (g != 44) PROCESSP(cs.y, cs.x, 1, p2_, q2_, C1, C2, C3, C4);
      }
      __syncthreads();
    }
#pragma unroll
    for (int t = 0; t < 2; t++) {
      int a = t ? a2 : a1;
      int X1 = 16 * a + lx, X2 = 511 - X1;
      int Y1 = 16 * a + ly, Y2 = 511 - Y1;
      int kx = 2 * X1 - 511, ky = 2 * Y1 - 511;
      bool in = (kx * kx + ky * ky) <= 261632;
      float g0x1 = f0[X1], g0x2 = f0[X2];
      float g90y1 = f90[Y1], g90y2 = f90[Y2];
      float P1 = (t ? C1 : A1) + g0x1 + g90y2;
      float P2 = (t ? C2 : A2) + g0x2 + g90y2;
      float P3 = (t ? C3 : A3) + g0x2 + g90y1;
      float P4 = (t ? C4 : A4) + g0x1 + g90y1;
      ob[(size_t)Y1 * DET + X1] = in ? P1 * SC : 0.f;
      ob[(size_t)Y1 * DET + X2] = in ? P2 * SC : 0.f;
      ob[(size_t)Y2 * DET + X2] = in ? P3 * SC : 0.f;
      ob[(size_t)Y2 * DET + X1] = in ? P4 * SC : 0.f;
    }
    return;
  }

  // ---- off-diagonal unit (a < bt): P-quad + transposed Q-quad ----
  int a = (bx>=6)+(bx>=14)+(bx>=24)+(bx>=35)+(bx>=46)+(bx>=56)+(bx>=65)
        + (bx>=73)+(bx>=80)+(bx>=86)+(bx>=91)+(bx>=95)+(bx>=98)+(bx>=100);
  int Sa, bs;
  if (a < 8) { Sa = (int)((0x41382E23180E0600ULL >> (8*a)) & 0xFF);
               bs = (int)((0x080706050506080AULL >> (8*a)) & 0xFF); }
  else       { Sa = (int)((0x0064625F5B565049ULL >> (8*(a-8))) & 0xFF);
               bs = (int)((0x000F0E0D0C0B0A09ULL >> (8*(a-8))) & 0xFF); }
  int bt = bx - Sa + bs;
  int tx = 16*a, ty = 16*bt;

  int X1 = tx + lx, X2 = 511 - X1;
  int Y1 = ty + ly, Y2 = 511 - Y1;
  float p_ = (float)X1 - 255.5f;
  float q_ = (float)Y1 - 255.5f;

  int mkx = 481 - 32*a;
  int mky = 505 - 32*bt - 8*w;
  bool wlive = (mkx*mkx + mky*mky <= 261632);

  float A1=0.f, A2=0.f, A3=0.f, A4=0.f;   // P-tile mirrors
  float B1=0.f, B2=0.f, B3=0.f, B4=0.f;   // Q (transposed) tile mirrors

  stage_group(0, 0);
  __syncthreads();   // covers stage(0) AND trigs fill

  for (int g = 0; g < NGP; g++) {
    if (g + 1 < NGP) stage_group(g + 1, (g + 1) & 1);
    float2 cs = trigs[g];
    const uint4* colI = &pk[g & 1][0];
    if (wlive) {
      PROCESS(cs.x, cs.y, 0);                    // tp = g
      if (g != 44) PROCESS(cs.y, cs.x, 1);       // tp = 88-g
    }
    __syncthreads();
  }

  // epilogue: singles t=0 / t=90, mask, scale
  int kx = 2*X1 - 511, ky = 2*Y1 - 511;
  bool in = (kx*kx + ky*ky) <= 261632;

  float g0x1 = f0[X1], g0x2 = f0[X2];
  float g90y1 = f90[Y1], g90y2 = f90[Y2];
  float P1 = A1 + g0x1 + g90y2;
  float P2 = A2 + g0x2 + g90y2;
  float P3 = A3 + g0x2 + g90y1;
  float P4 = A4 + g0x1 + g90y1;
  ob[(size_t)Y1*DET + X1] = in ? P1*SC : 0.f;
  ob[(size_t)Y1*DET + X2] = in ? P2*SC : 0.f;
  ob[(size_t)Y2*DET + X2] = in ? P3*SC : 0.f;
  ob[(size_t)Y2*DET + X1] = in ? P4*SC : 0.f;

  {
    float g0y1 = f0[Y1], g0y2 = f0[Y2];
    float g90x1 = f90[X1], g90x2 = f90[X2];
    float Q1 = B1 + g0y1 + g90x2;
    float Q2 = B2 + g0y1 + g90x1;
    float Q3 = B3 + g0y2 + g90x1;
    float Q4 = B4 + g0y2 + g90x2;
    Q1 = in ? Q1*SC : 0.f;
    Q2 = in ? Q2*SC : 0.f;
    Q3 = in ? Q3*SC : 0.f;
    Q4 = in ? Q4*SC : 0.f;
    __syncthreads();                                // pk free now
    float* qs = (float*)&pk[0][0];                  // [4][16][17] padded
    qs[(0*16 + lx)*17 + ly] = Q1;
    qs[(1*16 + lx)*17 + ly] = Q2;
    qs[(2*16 + lx)*17 + ly] = Q3;
    qs[(3*16 + lx)*17 + ly] = Q4;
    __syncthreads();
    float o1 = qs[(0*16 + ly)*17 + lx];
    float o2 = qs[(1*16 + ly)*17 + lx];
    float o3 = qs[(2*16 + ly)*17 + lx];
    float o4 = qs[(3*16 + ly)*17 + lx];
    int r1 = tx + ly, r2 = 511 - r1;
    int c1 = ty + lx, c2 = 511 - c1;
    ob[(size_t)r1*DET + c1] = o1;
    ob[(size_t)r2*DET + c1] = o2;
    ob[(size_t)r2*DET + c2] = o3;
    ob[(size_t)r1*DET + c2] = o4;
  }
}

extern "C" void kernel_launch(void* const* d_in, const int* in_sizes, int n_in,
                              void* d_out, int out_size, void* d_ws, size_t ws_size,
                              hipStream_t stream) {
  (void)in_sizes; (void)n_in; (void)out_size; (void)ws_size;
  const float* x = (const float*)d_in[0];
  float* out = (float*)d_out;
  char*  wsb = (char*)d_ws;

  filter_kernel<<<dim3(12, 16, 4), 256, 0, stream>>>(x, wsb);
  backproj_kernel<<<dim3(NBX * NB), 256, 0, stream>>>(wsb, out);
}